// Round 1
// baseline (916.157 us; speedup 1.0000x reference)
//
#include <hip/hip_runtime.h>
#include <hip/hip_bf16.h>
#include <math.h>

// Problem dims (fixed by the reference)
#define BB   8
#define NN   2048
#define CC   256            // CIN == H == UNITS == 256
#define MTOT (BB * NN)      // 16384 total rows

// ---------------------------------------------------------------------------
// Generic Y = relu(A @ W + bias); A: Mx256 row-major, W: 256x256, Y: Mx256.
// 64x64 output tile per 256-thread block, 4x4 register blocking, K-tiles of 16.
// ---------------------------------------------------------------------------
__global__ __launch_bounds__(256)
void gemm_nn_bias_relu(const float* __restrict__ A, const float* __restrict__ W,
                       const float* __restrict__ bias, float* __restrict__ out)
{
    const int row0 = blockIdx.y * 64;
    const int col0 = blockIdx.x * 64;
    __shared__ float As[64][17];   // +1 pad breaks pow2 stride
    __shared__ float Bs[16][65];
    const int tid = threadIdx.x;
    const int tx = tid & 15, ty = tid >> 4;
    float acc[4][4] = {};
    for (int k0 = 0; k0 < 256; k0 += 16) {
#pragma unroll
        for (int i = 0; i < 4; ++i) {          // 1024 elems / 256 threads
            int idx = tid + i * 256;
            int r = idx >> 4, c = idx & 15;
            As[r][c] = A[(size_t)(row0 + r) * 256 + (k0 + c)];
        }
#pragma unroll
        for (int i = 0; i < 4; ++i) {
            int idx = tid + i * 256;
            int r = idx >> 6, c = idx & 63;
            Bs[r][c] = W[(size_t)(k0 + r) * 256 + (col0 + c)];
        }
        __syncthreads();
#pragma unroll
        for (int kk = 0; kk < 16; ++kk) {
            float a[4], b[4];
#pragma unroll
            for (int i = 0; i < 4; ++i) a[i] = As[ty * 4 + i][kk];
#pragma unroll
            for (int j = 0; j < 4; ++j) b[j] = Bs[kk][tx * 4 + j];
#pragma unroll
            for (int i = 0; i < 4; ++i)
#pragma unroll
                for (int j = 0; j < 4; ++j)
                    acc[i][j] = fmaf(a[i], b[j], acc[i][j]);
        }
        __syncthreads();
    }
#pragma unroll
    for (int i = 0; i < 4; ++i) {
        const int r = row0 + ty * 4 + i;
#pragma unroll
        for (int j = 0; j < 4; ++j) {
            const int c = col0 + tx * 4 + j;
            float v = acc[i][j] + bias[c];
            out[(size_t)r * 256 + c] = v > 0.0f ? v : 0.0f;
        }
    }
}

// ---------------------------------------------------------------------------
// S[b,n,m] = sum_h K[b,n,h] * Q[b,m,h]  (NT GEMM per batch, K-dim = h = 256)
// ---------------------------------------------------------------------------
__global__ __launch_bounds__(256)
void score_kernel(const float* __restrict__ K, const float* __restrict__ Q,
                  float* __restrict__ S)
{
    const int b  = blockIdx.z;
    const int n0 = blockIdx.y * 64;
    const int m0 = blockIdx.x * 64;
    const float* Kb = K + (size_t)b * NN * 256;
    const float* Qb = Q + (size_t)b * NN * 256;
    float*       Sb = S + (size_t)b * NN * NN;
    __shared__ float Ks[64][17];
    __shared__ float Qs[64][17];
    const int tid = threadIdx.x;
    const int tx = tid & 15, ty = tid >> 4;
    float acc[4][4] = {};
    for (int h0 = 0; h0 < 256; h0 += 16) {
#pragma unroll
        for (int i = 0; i < 4; ++i) {
            int idx = tid + i * 256;
            int r = idx >> 4, c = idx & 15;
            Ks[r][c] = Kb[(size_t)(n0 + r) * 256 + (h0 + c)];
            Qs[r][c] = Qb[(size_t)(m0 + r) * 256 + (h0 + c)];
        }
        __syncthreads();
#pragma unroll
        for (int kk = 0; kk < 16; ++kk) {
            float a[4], bq[4];
#pragma unroll
            for (int i = 0; i < 4; ++i) a[i] = Ks[ty * 4 + i][kk];
#pragma unroll
            for (int j = 0; j < 4; ++j) bq[j] = Qs[tx * 4 + j][kk];
#pragma unroll
            for (int i = 0; i < 4; ++i)
#pragma unroll
                for (int j = 0; j < 4; ++j)
                    acc[i][j] = fmaf(a[i], bq[j], acc[i][j]);
        }
        __syncthreads();
    }
#pragma unroll
    for (int i = 0; i < 4; ++i)
#pragma unroll
        for (int j = 0; j < 4; ++j)
            Sb[(size_t)(n0 + ty * 4 + i) * NN + (m0 + tx * 4 + j)] = acc[i][j];
}

// ---------------------------------------------------------------------------
// In-place row softmax over last axis (rows of length 2048). One block/row.
// ---------------------------------------------------------------------------
__global__ __launch_bounds__(256)
void softmax_rows(float* __restrict__ S)
{
    float* row = S + (size_t)blockIdx.x * NN;
    const int tid = threadIdx.x;
    float v[8];
    float mx = -1e30f;
#pragma unroll
    for (int i = 0; i < 8; ++i) {
        v[i] = row[tid + i * 256];
        mx = fmaxf(mx, v[i]);
    }
    __shared__ float red[256];
    red[tid] = mx;
    __syncthreads();
    for (int s = 128; s >= 1; s >>= 1) {
        if (tid < s) red[tid] = fmaxf(red[tid], red[tid + s]);
        __syncthreads();
    }
    mx = red[0];
    __syncthreads();
    float sum = 0.f;
#pragma unroll
    for (int i = 0; i < 8; ++i) {
        v[i] = __expf(v[i] - mx);
        sum += v[i];
    }
    red[tid] = sum;
    __syncthreads();
    for (int s = 128; s >= 1; s >>= 1) {
        if (tid < s) red[tid] += red[tid + s];
        __syncthreads();
    }
    const float inv = 1.0f / red[0];
#pragma unroll
    for (int i = 0; i < 8; ++i)
        row[tid + i * 256] = v[i] * inv;
}

// ---------------------------------------------------------------------------
// att[b,m,h] = sum_n P[b,n,m] * V[b,n,h]   (TN GEMM per batch, K-dim = n)
// ---------------------------------------------------------------------------
__global__ __launch_bounds__(256)
void att_kernel(const float* __restrict__ P, const float* __restrict__ V,
                float* __restrict__ att)
{
    const int b  = blockIdx.z;
    const int m0 = blockIdx.y * 64;
    const int h0 = blockIdx.x * 64;
    const float* Pb = P + (size_t)b * NN * NN;
    const float* Vb = V + (size_t)b * NN * 256;
    float*     attb = att + (size_t)b * NN * 256;
    __shared__ float Ps[16][65];
    __shared__ float Vs[16][65];
    const int tid = threadIdx.x;
    const int tx = tid & 15, ty = tid >> 4;
    float acc[4][4] = {};
    for (int n0 = 0; n0 < NN; n0 += 16) {
#pragma unroll
        for (int i = 0; i < 4; ++i) {
            int idx = tid + i * 256;
            int r = idx >> 6, c = idx & 63;
            Ps[r][c] = Pb[(size_t)(n0 + r) * NN + (m0 + c)];
            Vs[r][c] = Vb[(size_t)(n0 + r) * 256 + (h0 + c)];
        }
        __syncthreads();
#pragma unroll
        for (int kk = 0; kk < 16; ++kk) {
            float a[4], bv[4];
#pragma unroll
            for (int i = 0; i < 4; ++i) a[i] = Ps[kk][ty * 4 + i];
#pragma unroll
            for (int j = 0; j < 4; ++j) bv[j] = Vs[kk][tx * 4 + j];
#pragma unroll
            for (int i = 0; i < 4; ++i)
#pragma unroll
                for (int j = 0; j < 4; ++j)
                    acc[i][j] = fmaf(a[i], bv[j], acc[i][j]);
        }
        __syncthreads();
    }
#pragma unroll
    for (int i = 0; i < 4; ++i)
#pragma unroll
        for (int j = 0; j < 4; ++j)
            attb[(size_t)(m0 + ty * 4 + i) * 256 + (h0 + tx * 4 + j)] = acc[i][j];
}

extern "C" void kernel_launch(void* const* d_in, const int* in_sizes, int n_in,
                              void* d_out, int out_size, void* d_ws, size_t ws_size,
                              hipStream_t stream)
{
    (void)in_sizes; (void)n_in; (void)out_size; (void)ws_size;
    const float* x  = (const float*)d_in[0];
    const float* Wq = (const float*)d_in[1];
    const float* bq = (const float*)d_in[2];
    const float* Wk = (const float*)d_in[3];
    const float* bk = (const float*)d_in[4];
    const float* Wm = (const float*)d_in[5];
    const float* bm = (const float*)d_in[6];
    float* out = (float*)d_out;

    // Workspace layout (fp32): q | k | att | S(=P in-place)
    // bytes: 3 * 16.78 MB + 134.2 MB = 184.5 MB  (requires ws_size >= that)
    float* q   = (float*)d_ws;
    float* k   = q   + (size_t)MTOT * 256;
    float* att = k   + (size_t)MTOT * 256;
    float* S   = att + (size_t)MTOT * 256;

    dim3 blk(256);
    // q = relu(x@Wq+bq), k = relu(x@Wk+bk)
    gemm_nn_bias_relu<<<dim3(4, MTOT / 64), blk, 0, stream>>>(x, Wq, bq, q);
    gemm_nn_bias_relu<<<dim3(4, MTOT / 64), blk, 0, stream>>>(x, Wk, bk, k);
    // S[b,n,m] = k . q
    score_kernel<<<dim3(NN / 64, NN / 64, BB), blk, 0, stream>>>(k, q, S);
    // P = softmax(S, axis=-1), in place
    softmax_rows<<<dim3(MTOT), blk, 0, stream>>>(S);
    // att[b,m,h] = sum_n P[b,n,m] * q[b,n,h]   (v = q in the reference)
    att_kernel<<<dim3(256 / 64, NN / 64, BB), blk, 0, stream>>>(S, q, att);
    // out = relu(att@Wm+bm)
    gemm_nn_bias_relu<<<dim3(4, MTOT / 64), blk, 0, stream>>>(att, Wm, bm, out);
}

// Round 2
// 392.450 us; speedup vs baseline: 2.3345x; 2.3345x over previous
//
#include <hip/hip_runtime.h>
#include <hip/hip_bf16.h>
#include <math.h>

#define BB   8
#define NN   2048
#define CC   256
#define MTOT (BB * NN)   // 16384

typedef __bf16 bf16_t;
typedef bf16_t bf16x8 __attribute__((ext_vector_type(8)));
typedef float  floatx4 __attribute__((ext_vector_type(4)));

// async global->LDS, 16 bytes per lane. LDS dest must be wave-uniform-base + lane*16.
__device__ __forceinline__ void gl_lds16(const bf16_t* g, bf16_t* l) {
    __builtin_amdgcn_global_load_lds(
        (const __attribute__((address_space(1))) unsigned int*)g,
        (__attribute__((address_space(3))) unsigned int*)l, 16, 0, 0);
}

// ---------------------------------------------------------------------------
// NT bf16 GEMM: C[m][n] = sum_k A[m][k] * B[n][k]  (+bias, relu optional)
// 128x128 tile, K fixed = 256, 256 threads (2x2 waves of 64x64), 16x16x32 MFMA.
// ---------------------------------------------------------------------------
template<bool OUT_F32, bool BIASRELU>
__global__ __launch_bounds__(256, 3)
void gemm_nt(const bf16_t* __restrict__ A, const bf16_t* __restrict__ B,
             void* __restrict__ C, const float* __restrict__ bias,
             int lda, int ldb, int ldc,
             long strideA, long strideB, long strideC)
{
    const int b = blockIdx.z;
    A += (long)b * strideA;
    B += (long)b * strideB;
    const int m0 = blockIdx.y * 128;
    const int n0 = blockIdx.x * 128;

    __shared__ bf16_t As[128 * 32];   // [row][k] 32 k's (64 B) per row
    __shared__ bf16_t Bs[128 * 32];

    const int tid  = threadIdx.x;
    const int wid  = tid >> 6, lane = tid & 63;
    const int wm   = (wid >> 1) * 64, wn = (wid & 1) * 64;
    const int fr   = lane & 15;            // fragment row/col within 16
    const int kb   = (lane >> 4) * 8;      // k base within 32

    floatx4 acc[4][4] = {};

    for (int k0 = 0; k0 < 256; k0 += 32) {
#pragma unroll
        for (int r = 0; r < 2; ++r) {
            const int lin = tid + r * 256;          // 512 chunks of 16B
            const int rw  = lin >> 2, kc = lin & 3;
            gl_lds16(A + (long)(m0 + rw) * lda + k0 + kc * 8, As + lin * 8);
            gl_lds16(B + (long)(n0 + rw) * ldb + k0 + kc * 8, Bs + lin * 8);
        }
        __syncthreads();
        bf16x8 af[4], bf[4];
#pragma unroll
        for (int f = 0; f < 4; ++f) {
            af[f] = *(const bf16x8*)(As + (wm + f * 16 + fr) * 32 + kb);
            bf[f] = *(const bf16x8*)(Bs + (wn + f * 16 + fr) * 32 + kb);
        }
#pragma unroll
        for (int f = 0; f < 4; ++f)
#pragma unroll
            for (int g = 0; g < 4; ++g)
                acc[f][g] = __builtin_amdgcn_mfma_f32_16x16x32_bf16(af[f], bf[g], acc[f][g], 0, 0, 0);
        __syncthreads();
    }

    // C/D layout: col = lane&15, row = (lane>>4)*4 + reg
    const int rbase = (lane >> 4) * 4;
#pragma unroll
    for (int g = 0; g < 4; ++g) {
        const int n = n0 + wn + g * 16 + fr;
        const float bv = BIASRELU ? bias[n] : 0.0f;
#pragma unroll
        for (int f = 0; f < 4; ++f) {
#pragma unroll
            for (int r = 0; r < 4; ++r) {
                const int m = m0 + wm + f * 16 + rbase + r;
                float v = acc[f][g][r] + bv;
                if (BIASRELU) v = v > 0.0f ? v : 0.0f;
                if (OUT_F32)
                    ((float*)C)[(long)b * strideC + (long)m * ldc + n] = v;
                else
                    ((bf16_t*)C)[(long)b * strideC + (long)m * ldc + n] = (bf16_t)v;
            }
        }
    }
}

// ---------------------------------------------------------------------------
// Per-column softmax stats of St: for fixed n, over rows m: mx[n], invl[n].
// St per batch: 2048x2048 fp32. Block = 64 columns, grid (32, BB).
// ---------------------------------------------------------------------------
__global__ __launch_bounds__(256)
void col_stats(const float* __restrict__ St, float* __restrict__ mx,
               float* __restrict__ invl)
{
    const int b  = blockIdx.y;
    const int n0 = blockIdx.x * 64;
    const float* S = St + (long)b * NN * NN;
    const int c = threadIdx.x & 63, rg = threadIdx.x >> 6;

    float m = -1e30f, l = 0.0f;
    for (int mi = rg; mi < NN; mi += 4) {
        const float v = S[(long)mi * NN + n0 + c];
        const float nm = fmaxf(m, v);
        l = l * __expf(m - nm) + __expf(v - nm);
        m = nm;
    }
    __shared__ float sm[4][64], sl[4][64];
    sm[rg][c] = m; sl[rg][c] = l;
    __syncthreads();
    if (rg == 0) {
        float M = sm[0][c], L = sl[0][c];
#pragma unroll
        for (int r = 1; r < 4; ++r) {
            const float m2 = sm[r][c], l2 = sl[r][c];
            const float nm = fmaxf(M, m2);
            L = L * __expf(M - nm) + l2 * __expf(m2 - nm);
            M = nm;
        }
        mx[b * NN + n0 + c]   = M;
        invl[b * NN + n0 + c] = 1.0f / L;
    }
}

// ---------------------------------------------------------------------------
// att[m][h] = sum_n exp(St[m][n]-mx[n])*invl[n] * qT[h][n]   (bf16 MFMA)
// Block tile: 64 m x 256 h, K-loop over n in steps of 32. P never materialized.
// ---------------------------------------------------------------------------
__global__ __launch_bounds__(256, 3)
void att_gemm(const float* __restrict__ St, const bf16_t* __restrict__ qT,
              const float* __restrict__ mx, const float* __restrict__ invl,
              bf16_t* __restrict__ att)
{
    const int b  = blockIdx.y;
    const int m0 = blockIdx.x * 64;
    const float*  S  = St  + (long)b * NN * NN;
    const bf16_t* Q  = qT  + (long)b * 256 * NN;
    const float*  MX = mx  + b * NN;
    const float*  IL = invl + b * NN;
    bf16_t*       O  = att + (long)b * NN * 256;

    __shared__ bf16_t As[64 * 32];    // 4 KB: P-tile (exp'd, bf16)
    __shared__ bf16_t Bs[256 * 32];   // 16 KB: qT tile

    const int tid  = threadIdx.x;
    const int wid  = tid >> 6, lane = tid & 63;
    const int wn   = wid * 64;             // h-range per wave
    const int fr   = lane & 15;
    const int kb   = (lane >> 4) * 8;
    const int arow = tid >> 2;             // 0..63
    const int aseg = tid & 3;              // 8 floats each

    floatx4 acc[4][4] = {};   // [f: m][g: h]

    for (int n0 = 0; n0 < NN; n0 += 32) {
#pragma unroll
        for (int r = 0; r < 4; ++r) {            // qT: 256 rows x 64 B
            const int lin = tid + r * 256;
            const int rw  = lin >> 2, kc = lin & 3;
            gl_lds16(Q + (long)rw * NN + n0 + kc * 8, Bs + lin * 8);
        }
        // A: load St 64x32 fp32, apply exp((s-mx)*1)*invl, pack bf16
        const float4 v0 = *(const float4*)(S + (long)(m0 + arow) * NN + n0 + aseg * 8);
        const float4 v1 = *(const float4*)(S + (long)(m0 + arow) * NN + n0 + aseg * 8 + 4);
        const float4 x0 = *(const float4*)(MX + n0 + aseg * 8);
        const float4 x1 = *(const float4*)(MX + n0 + aseg * 8 + 4);
        const float4 i0 = *(const float4*)(IL + n0 + aseg * 8);
        const float4 i1 = *(const float4*)(IL + n0 + aseg * 8 + 4);
        bf16x8 p;
        p[0] = (bf16_t)(__expf(v0.x - x0.x) * i0.x);
        p[1] = (bf16_t)(__expf(v0.y - x0.y) * i0.y);
        p[2] = (bf16_t)(__expf(v0.z - x0.z) * i0.z);
        p[3] = (bf16_t)(__expf(v0.w - x0.w) * i0.w);
        p[4] = (bf16_t)(__expf(v1.x - x1.x) * i1.x);
        p[5] = (bf16_t)(__expf(v1.y - x1.y) * i1.y);
        p[6] = (bf16_t)(__expf(v1.z - x1.z) * i1.z);
        p[7] = (bf16_t)(__expf(v1.w - x1.w) * i1.w);
        *(bf16x8*)(As + arow * 32 + aseg * 8) = p;
        __syncthreads();

        bf16x8 af[4], bf[4];
#pragma unroll
        for (int f = 0; f < 4; ++f) {
            af[f] = *(const bf16x8*)(As + (f * 16 + fr) * 32 + kb);
            bf[f] = *(const bf16x8*)(Bs + (wn + f * 16 + fr) * 32 + kb);
        }
#pragma unroll
        for (int f = 0; f < 4; ++f)
#pragma unroll
            for (int g = 0; g < 4; ++g)
                acc[f][g] = __builtin_amdgcn_mfma_f32_16x16x32_bf16(af[f], bf[g], acc[f][g], 0, 0, 0);
        __syncthreads();
    }

    const int rbase = (lane >> 4) * 4;
#pragma unroll
    for (int f = 0; f < 4; ++f)
#pragma unroll
        for (int g = 0; g < 4; ++g)
#pragma unroll
            for (int r = 0; r < 4; ++r) {
                const int m = m0 + f * 16 + rbase + r;
                const int h = wn + g * 16 + fr;
                O[(long)m * 256 + h] = (bf16_t)acc[f][g][r];
            }
}

// ---------------------------------------------------------------------------
// Small helpers: fp32->bf16 convert; W (KxN fp32) -> Wt (NxK bf16);
// q (n,h bf16) -> qT (h,n bf16) per batch.
// ---------------------------------------------------------------------------
__global__ __launch_bounds__(256)
void cvt_bf16(const float* __restrict__ x, bf16_t* __restrict__ y)
{
    const long i = ((long)blockIdx.x * 256 + threadIdx.x) * 8;
    const float4 a = *(const float4*)(x + i);
    const float4 b = *(const float4*)(x + i + 4);
    bf16x8 o;
    o[0] = (bf16_t)a.x; o[1] = (bf16_t)a.y; o[2] = (bf16_t)a.z; o[3] = (bf16_t)a.w;
    o[4] = (bf16_t)b.x; o[5] = (bf16_t)b.y; o[6] = (bf16_t)b.z; o[7] = (bf16_t)b.w;
    *(bf16x8*)(y + i) = o;
}

__global__ __launch_bounds__(256)
void transpose_w(const float* __restrict__ W, bf16_t* __restrict__ Wt)
{
    __shared__ float t[32][33];
    const int n0 = blockIdx.x * 32, k0 = blockIdx.y * 32;
    const int tx = threadIdx.x & 31, ty = threadIdx.x >> 5;
    for (int i = ty; i < 32; i += 8) t[i][tx] = W[(k0 + i) * 256 + n0 + tx];
    __syncthreads();
    for (int i = ty; i < 32; i += 8) Wt[(n0 + i) * 256 + k0 + tx] = (bf16_t)t[tx][i];
}

__global__ __launch_bounds__(256)
void transpose_q(const bf16_t* __restrict__ q, bf16_t* __restrict__ qT)
{
    const int b = blockIdx.z;
    const bf16_t* qb = q + (long)b * NN * 256;
    bf16_t* qTb = qT + (long)b * 256 * NN;
    __shared__ bf16_t t[32][33];
    const int n0 = blockIdx.x * 32, h0 = blockIdx.y * 32;
    const int tx = threadIdx.x & 31, ty = threadIdx.x >> 5;
    for (int i = ty; i < 32; i += 8) t[i][tx] = qb[(long)(n0 + i) * 256 + h0 + tx];
    __syncthreads();
    for (int i = ty; i < 32; i += 8) qTb[(long)(h0 + i) * NN + n0 + tx] = t[tx][i];
}

extern "C" void kernel_launch(void* const* d_in, const int* in_sizes, int n_in,
                              void* d_out, int out_size, void* d_ws, size_t ws_size,
                              hipStream_t stream)
{
    (void)in_sizes; (void)n_in; (void)out_size; (void)ws_size;
    const float* x  = (const float*)d_in[0];
    const float* Wq = (const float*)d_in[1];
    const float* bq = (const float*)d_in[2];
    const float* Wk = (const float*)d_in[3];
    const float* bk = (const float*)d_in[4];
    const float* Wm = (const float*)d_in[5];
    const float* bm = (const float*)d_in[6];
    float* out = (float*)d_out;

    // Workspace layout: St fp32 (134.2 MB) | 5 bf16 tensors (8.39 MB each) |
    // 3 bf16 weights (128 KB) | stats (2 x 64 KB). Total ~176.7 MB.
    char* w = (char*)d_ws;
    float*  St     = (float*)w;                     w += (size_t)BB * NN * NN * 4;
    bf16_t* x_bf   = (bf16_t*)w;                    w += (size_t)MTOT * 256 * 2;
    bf16_t* q_bf   = (bf16_t*)w;                    w += (size_t)MTOT * 256 * 2;
    bf16_t* k_bf   = (bf16_t*)w;                    w += (size_t)MTOT * 256 * 2;
    bf16_t* qT     = (bf16_t*)w;                    w += (size_t)MTOT * 256 * 2;
    bf16_t* att_bf = (bf16_t*)w;                    w += (size_t)MTOT * 256 * 2;
    bf16_t* WqT    = (bf16_t*)w;                    w += 256 * 256 * 2;
    bf16_t* WkT    = (bf16_t*)w;                    w += 256 * 256 * 2;
    bf16_t* WmT    = (bf16_t*)w;                    w += 256 * 256 * 2;
    float*  mxb    = (float*)w;                     w += MTOT * 4;
    float*  ilb    = (float*)w;

    cvt_bf16<<<dim3(MTOT * 256 / (256 * 8)), 256, 0, stream>>>(x, x_bf);
    transpose_w<<<dim3(8, 8), 256, 0, stream>>>(Wq, WqT);
    transpose_w<<<dim3(8, 8), 256, 0, stream>>>(Wk, WkT);
    transpose_w<<<dim3(8, 8), 256, 0, stream>>>(Wm, WmT);

    // q = relu(x@Wq+bq), k = relu(x@Wk+bk)  [bf16 out]
    gemm_nt<false, true><<<dim3(2, 128, 1), 256, 0, stream>>>(
        x_bf, WqT, q_bf, bq, 256, 256, 256, 0, 0, 0);
    gemm_nt<false, true><<<dim3(2, 128, 1), 256, 0, stream>>>(
        x_bf, WkT, k_bf, bk, 256, 256, 256, 0, 0, 0);

    transpose_q<<<dim3(64, 8, 8), 256, 0, stream>>>(q_bf, qT);

    // St[m][n] = sum_h q[m,h] k[n,h]  (fp32 out)
    gemm_nt<true, false><<<dim3(16, 16, BB), 256, 0, stream>>>(
        q_bf, k_bf, St, nullptr, 256, 256, NN,
        (long)NN * 256, (long)NN * 256, (long)NN * NN);

    col_stats<<<dim3(32, BB), 256, 0, stream>>>(St, mxb, ilb);

    // att[m][h] = sum_n P[n][m] * q[n][h]  (softmax fused into staging)
    att_gemm<<<dim3(32, BB), 256, 0, stream>>>(St, qT, mxb, ilb, att_bf);

    // out = relu(att@Wm+bm)  [fp32 out]
    gemm_nt<true, true><<<dim3(2, 128, 1), 256, 0, stream>>>(
        att_bf, WmT, out, bm, 256, 256, 256, 0, 0, 0);
}

// Round 3
// 230.462 us; speedup vs baseline: 3.9753x; 1.7029x over previous
//
#include <hip/hip_runtime.h>
#include <hip/hip_bf16.h>
#include <math.h>

#define BB   8
#define NN   2048
#define CC   256
#define MTOT (BB * NN)   // 16384

typedef __bf16 bf16_t;
typedef bf16_t bf16x8 __attribute__((ext_vector_type(8)));
typedef float  floatx4 __attribute__((ext_vector_type(4)));

// async global->LDS, 16 bytes per lane. LDS dest must be wave-uniform-base + lane*16.
__device__ __forceinline__ void gl_lds16(const bf16_t* g, bf16_t* l) {
    __builtin_amdgcn_global_load_lds(
        (const __attribute__((address_space(1))) unsigned int*)g,
        (__attribute__((address_space(3))) unsigned int*)l, 16, 0, 0);
}

// ---------------------------------------------------------------------------
// NT bf16 GEMM: C[m][n] = sum_k A[m][k] * B[n][k]  (+bias, relu optional)
// 128x128 tile, K fixed = 256, 256 threads (2x2 waves of 64x64), 16x16x32 MFMA.
// DO_STATS: also emit per-column (max, sumexp) partials over this block's 128
// rows, for a later softmax-over-rows — fused into the epilogue (no re-read).
// ---------------------------------------------------------------------------
template<bool OUT_F32, bool BIASRELU, bool DO_STATS>
__global__ __launch_bounds__(256, 3)
void gemm_nt(const bf16_t* __restrict__ A, const bf16_t* __restrict__ B,
             void* __restrict__ C, const float* __restrict__ bias,
             int lda, int ldb, int ldc,
             long strideA, long strideB, long strideC,
             float* __restrict__ pm, float* __restrict__ pl)
{
    const int b = blockIdx.z;
    A += (long)b * strideA;
    B += (long)b * strideB;
    const int m0 = blockIdx.y * 128;
    const int n0 = blockIdx.x * 128;

    __shared__ bf16_t As[128 * 32];   // [row][k] 32 k's (64 B) per row
    __shared__ bf16_t Bs[128 * 32];
    __shared__ float  smx[4][4][16];  // [wid][g][fr] epilogue stats merge
    __shared__ float  ssm[4][4][16];

    const int tid  = threadIdx.x;
    const int wid  = tid >> 6, lane = tid & 63;
    const int wm   = (wid >> 1) * 64, wn = (wid & 1) * 64;
    const int fr   = lane & 15;            // fragment row/col within 16
    const int kb   = (lane >> 4) * 8;      // k base within 32

    floatx4 acc[4][4] = {};

    for (int k0 = 0; k0 < 256; k0 += 32) {
#pragma unroll
        for (int r = 0; r < 2; ++r) {
            const int lin = tid + r * 256;          // 512 chunks of 16B
            const int rw  = lin >> 2, kc = lin & 3;
            gl_lds16(A + (long)(m0 + rw) * lda + k0 + kc * 8, As + lin * 8);
            gl_lds16(B + (long)(n0 + rw) * ldb + k0 + kc * 8, Bs + lin * 8);
        }
        __syncthreads();
        bf16x8 af[4], bf[4];
#pragma unroll
        for (int f = 0; f < 4; ++f) {
            af[f] = *(const bf16x8*)(As + (wm + f * 16 + fr) * 32 + kb);
            bf[f] = *(const bf16x8*)(Bs + (wn + f * 16 + fr) * 32 + kb);
        }
#pragma unroll
        for (int f = 0; f < 4; ++f)
#pragma unroll
            for (int g = 0; g < 4; ++g)
                acc[f][g] = __builtin_amdgcn_mfma_f32_16x16x32_bf16(af[f], bf[g], acc[f][g], 0, 0, 0);
        __syncthreads();
    }

    // C/D layout: col = lane&15, row = (lane>>4)*4 + reg
    const int rbase = (lane >> 4) * 4;
#pragma unroll
    for (int g = 0; g < 4; ++g) {
        const int n = n0 + wn + g * 16 + fr;
        const float bv = BIASRELU ? bias[n] : 0.0f;
#pragma unroll
        for (int f = 0; f < 4; ++f) {
#pragma unroll
            for (int r = 0; r < 4; ++r) {
                const int m = m0 + wm + f * 16 + rbase + r;
                float v = acc[f][g][r] + bv;
                if (BIASRELU) v = v > 0.0f ? v : 0.0f;
                if (OUT_F32)
                    ((float*)C)[(long)b * strideC + (long)m * ldc + n] = v;
                else
                    ((bf16_t*)C)[(long)b * strideC + (long)m * ldc + n] = (bf16_t)v;
            }
        }
    }

    if (DO_STATS) {
        // Per-column max/sumexp over this block's 128 rows.
        // Stage 1: in-lane over f,r (16 values), then across u = lane>>4 via shfl.
        float lmax[4], lsum[4];
#pragma unroll
        for (int g = 0; g < 4; ++g) {
            float m = -1e30f;
#pragma unroll
            for (int f = 0; f < 4; ++f)
#pragma unroll
                for (int r = 0; r < 4; ++r) m = fmaxf(m, acc[f][g][r]);
            m = fmaxf(m, __shfl_xor(m, 16));
            m = fmaxf(m, __shfl_xor(m, 32));
            float s = 0.0f;
#pragma unroll
            for (int f = 0; f < 4; ++f)
#pragma unroll
                for (int r = 0; r < 4; ++r) s += __expf(acc[f][g][r] - m);
            s += __shfl_xor(s, 16);
            s += __shfl_xor(s, 32);
            lmax[g] = m; lsum[g] = s;
        }
        if (lane < 16) {
#pragma unroll
            for (int g = 0; g < 4; ++g) {
                smx[wid][g][lane] = lmax[g];
                ssm[wid][g][lane] = lsum[g];
            }
        }
        __syncthreads();
        // Stage 2: merge wave pairs sharing the same wn: (0,2) wn=0, (1,3) wn=64
        if (tid < 128) {
            const int pair = tid >> 6;       // which wn half
            const int idx  = tid & 63;
            const int g = idx >> 4, f2 = idx & 15;
            const float m0v = smx[pair][g][f2], m1v = smx[pair + 2][g][f2];
            const float M = fmaxf(m0v, m1v);
            const float L = ssm[pair][g][f2] * __expf(m0v - M) +
                            ssm[pair + 2][g][f2] * __expf(m1v - M);
            const int n = n0 + pair * 64 + g * 16 + f2;
            const long o = ((long)b * 16 + blockIdx.y) * NN + n;
            pm[o] = M;
            pl[o] = L;
        }
    }
}

// ---------------------------------------------------------------------------
// Merge 16 per-m-tile partials per column into (mx, invl). 16384 columns.
// ---------------------------------------------------------------------------
__global__ __launch_bounds__(256)
void stats_combine(const float* __restrict__ pm, const float* __restrict__ pl,
                   float* __restrict__ mx, float* __restrict__ invl)
{
    const int i = blockIdx.x * 256 + threadIdx.x;   // b*2048 + n
    const int b = i >> 11, n = i & 2047;
    float M = -1e30f, L = 0.0f;
#pragma unroll
    for (int t = 0; t < 16; ++t) {
        const long o = ((long)b * 16 + t) * NN + n;
        const float m = pm[o], l = pl[o];
        const float nm = fmaxf(M, m);
        L = L * __expf(M - nm) + l * __expf(m - nm);
        M = nm;
    }
    mx[i]   = M;
    invl[i] = 1.0f / L;
}

// ---------------------------------------------------------------------------
// att[m][h] = sum_n exp(St[m][n]-mx[n])*invl[n] * qT[h][n]   (bf16 MFMA)
// Block tile: 64 m x 256 h, K-loop over n in steps of 32. P never materialized.
// ---------------------------------------------------------------------------
__global__ __launch_bounds__(256, 3)
void att_gemm(const float* __restrict__ St, const bf16_t* __restrict__ qT,
              const float* __restrict__ mx, const float* __restrict__ invl,
              bf16_t* __restrict__ att)
{
    const int b  = blockIdx.y;
    const int m0 = blockIdx.x * 64;
    const float*  S  = St  + (long)b * NN * NN;
    const bf16_t* Q  = qT  + (long)b * 256 * NN;
    const float*  MX = mx  + b * NN;
    const float*  IL = invl + b * NN;
    bf16_t*       O  = att + (long)b * NN * 256;

    __shared__ bf16_t As[64 * 32];    // 4 KB: P-tile (exp'd, bf16)
    __shared__ bf16_t Bs[256 * 32];   // 16 KB: qT tile

    const int tid  = threadIdx.x;
    const int wid  = tid >> 6, lane = tid & 63;
    const int wn   = wid * 64;             // h-range per wave
    const int fr   = lane & 15;
    const int kb   = (lane >> 4) * 8;
    const int arow = tid >> 2;             // 0..63
    const int aseg = tid & 3;              // 8 floats each

    floatx4 acc[4][4] = {};   // [f: m][g: h]

    for (int n0 = 0; n0 < NN; n0 += 32) {
#pragma unroll
        for (int r = 0; r < 4; ++r) {            // qT: 256 rows x 64 B
            const int lin = tid + r * 256;
            const int rw  = lin >> 2, kc = lin & 3;
            gl_lds16(Q + (long)rw * NN + n0 + kc * 8, Bs + lin * 8);
        }
        // A: load St 64x32 fp32, apply exp(s-mx)*invl, pack bf16
        const float4 v0 = *(const float4*)(S + (long)(m0 + arow) * NN + n0 + aseg * 8);
        const float4 v1 = *(const float4*)(S + (long)(m0 + arow) * NN + n0 + aseg * 8 + 4);
        const float4 x0 = *(const float4*)(MX + n0 + aseg * 8);
        const float4 x1 = *(const float4*)(MX + n0 + aseg * 8 + 4);
        const float4 i0 = *(const float4*)(IL + n0 + aseg * 8);
        const float4 i1 = *(const float4*)(IL + n0 + aseg * 8 + 4);
        bf16x8 p;
        p[0] = (bf16_t)(__expf(v0.x - x0.x) * i0.x);
        p[1] = (bf16_t)(__expf(v0.y - x0.y) * i0.y);
        p[2] = (bf16_t)(__expf(v0.z - x0.z) * i0.z);
        p[3] = (bf16_t)(__expf(v0.w - x0.w) * i0.w);
        p[4] = (bf16_t)(__expf(v1.x - x1.x) * i1.x);
        p[5] = (bf16_t)(__expf(v1.y - x1.y) * i1.y);
        p[6] = (bf16_t)(__expf(v1.z - x1.z) * i1.z);
        p[7] = (bf16_t)(__expf(v1.w - x1.w) * i1.w);
        *(bf16x8*)(As + arow * 32 + aseg * 8) = p;
        __syncthreads();

        bf16x8 af[4], bf[4];
#pragma unroll
        for (int f = 0; f < 4; ++f) {
            af[f] = *(const bf16x8*)(As + (f * 16 + fr) * 32 + kb);
            bf[f] = *(const bf16x8*)(Bs + (wn + f * 16 + fr) * 32 + kb);
        }
#pragma unroll
        for (int f = 0; f < 4; ++f)
#pragma unroll
            for (int g = 0; g < 4; ++g)
                acc[f][g] = __builtin_amdgcn_mfma_f32_16x16x32_bf16(af[f], bf[g], acc[f][g], 0, 0, 0);
        __syncthreads();
    }

    const int rbase = (lane >> 4) * 4;
#pragma unroll
    for (int f = 0; f < 4; ++f)
#pragma unroll
        for (int g = 0; g < 4; ++g)
#pragma unroll
            for (int r = 0; r < 4; ++r) {
                const int m = m0 + f * 16 + rbase + r;
                const int h = wn + g * 16 + fr;
                O[(long)m * 256 + h] = (bf16_t)acc[f][g][r];
            }
}

// ---------------------------------------------------------------------------
// Small helpers: fp32->bf16 convert; W (KxN fp32) -> Wt (NxK bf16);
// q (n,h bf16) -> qT (h,n bf16) per batch.
// ---------------------------------------------------------------------------
__global__ __launch_bounds__(256)
void cvt_bf16(const float* __restrict__ x, bf16_t* __restrict__ y)
{
    const long i = ((long)blockIdx.x * 256 + threadIdx.x) * 8;
    const float4 a = *(const float4*)(x + i);
    const float4 b = *(const float4*)(x + i + 4);
    bf16x8 o;
    o[0] = (bf16_t)a.x; o[1] = (bf16_t)a.y; o[2] = (bf16_t)a.z; o[3] = (bf16_t)a.w;
    o[4] = (bf16_t)b.x; o[5] = (bf16_t)b.y; o[6] = (bf16_t)b.z; o[7] = (bf16_t)b.w;
    *(bf16x8*)(y + i) = o;
}

__global__ __launch_bounds__(256)
void transpose_w(const float* __restrict__ W, bf16_t* __restrict__ Wt)
{
    __shared__ float t[32][33];
    const int n0 = blockIdx.x * 32, k0 = blockIdx.y * 32;
    const int tx = threadIdx.x & 31, ty = threadIdx.x >> 5;
    for (int i = ty; i < 32; i += 8) t[i][tx] = W[(k0 + i) * 256 + n0 + tx];
    __syncthreads();
    for (int i = ty; i < 32; i += 8) Wt[(n0 + i) * 256 + k0 + tx] = (bf16_t)t[tx][i];
}

__global__ __launch_bounds__(256)
void transpose_q(const bf16_t* __restrict__ q, bf16_t* __restrict__ qT)
{
    const int b = blockIdx.z;
    const bf16_t* qb = q + (long)b * NN * 256;
    bf16_t* qTb = qT + (long)b * 256 * NN;
    __shared__ bf16_t t[32][33];
    const int n0 = blockIdx.x * 32, h0 = blockIdx.y * 32;
    const int tx = threadIdx.x & 31, ty = threadIdx.x >> 5;
    for (int i = ty; i < 32; i += 8) t[i][tx] = qb[(long)(n0 + i) * 256 + h0 + tx];
    __syncthreads();
    for (int i = ty; i < 32; i += 8) qTb[(long)(h0 + i) * NN + n0 + tx] = t[tx][i];
}

extern "C" void kernel_launch(void* const* d_in, const int* in_sizes, int n_in,
                              void* d_out, int out_size, void* d_ws, size_t ws_size,
                              hipStream_t stream)
{
    (void)in_sizes; (void)n_in; (void)out_size; (void)ws_size;
    const float* x  = (const float*)d_in[0];
    const float* Wq = (const float*)d_in[1];
    const float* bq = (const float*)d_in[2];
    const float* Wk = (const float*)d_in[3];
    const float* bk = (const float*)d_in[4];
    const float* Wm = (const float*)d_in[5];
    const float* bm = (const float*)d_in[6];
    float* out = (float*)d_out;

    // Workspace: St fp32 (134.2 MB) | 5 bf16 tensors (8.39 MB each) |
    // 3 bf16 weights | stats partials (2 x 1 MB) | stats (2 x 64 KB). ~179 MB.
    char* w = (char*)d_ws;
    float*  St     = (float*)w;                     w += (size_t)BB * NN * NN * 4;
    bf16_t* x_bf   = (bf16_t*)w;                    w += (size_t)MTOT * 256 * 2;
    bf16_t* q_bf   = (bf16_t*)w;                    w += (size_t)MTOT * 256 * 2;
    bf16_t* k_bf   = (bf16_t*)w;                    w += (size_t)MTOT * 256 * 2;
    bf16_t* qT     = (bf16_t*)w;                    w += (size_t)MTOT * 256 * 2;
    bf16_t* att_bf = (bf16_t*)w;                    w += (size_t)MTOT * 256 * 2;
    bf16_t* WqT    = (bf16_t*)w;                    w += 256 * 256 * 2;
    bf16_t* WkT    = (bf16_t*)w;                    w += 256 * 256 * 2;
    bf16_t* WmT    = (bf16_t*)w;                    w += 256 * 256 * 2;
    float*  pm     = (float*)w;                     w += (size_t)BB * 16 * NN * 4;
    float*  pl     = (float*)w;                     w += (size_t)BB * 16 * NN * 4;
    float*  mxb    = (float*)w;                     w += MTOT * 4;
    float*  ilb    = (float*)w;

    cvt_bf16<<<dim3(MTOT * 256 / (256 * 8)), 256, 0, stream>>>(x, x_bf);
    transpose_w<<<dim3(8, 8), 256, 0, stream>>>(Wq, WqT);
    transpose_w<<<dim3(8, 8), 256, 0, stream>>>(Wk, WkT);
    transpose_w<<<dim3(8, 8), 256, 0, stream>>>(Wm, WmT);

    // q = relu(x@Wq+bq), k = relu(x@Wk+bk)  [bf16 out]
    gemm_nt<false, true, false><<<dim3(2, 128, 1), 256, 0, stream>>>(
        x_bf, WqT, q_bf, bq, 256, 256, 256, 0, 0, 0, nullptr, nullptr);
    gemm_nt<false, true, false><<<dim3(2, 128, 1), 256, 0, stream>>>(
        x_bf, WkT, k_bf, bk, 256, 256, 256, 0, 0, 0, nullptr, nullptr);

    transpose_q<<<dim3(64, 8, 8), 256, 0, stream>>>(q_bf, qT);

    // St[m][n] = sum_h q[m,h] k[n,h]  (fp32 out) + fused per-column stats
    gemm_nt<true, false, true><<<dim3(16, 16, BB), 256, 0, stream>>>(
        q_bf, k_bf, St, nullptr, 256, 256, NN,
        (long)NN * 256, (long)NN * 256, (long)NN * NN, pm, pl);

    stats_combine<<<dim3(MTOT / 256), 256, 0, stream>>>(pm, pl, mxb, ilb);

    // att[m][h] = sum_n P[n][m] * q[n][h]  (softmax fused into staging)
    att_gemm<<<dim3(32, BB), 256, 0, stream>>>(St, qT, mxb, ilb, att_bf);

    // out = relu(att@Wm+bm)  [fp32 out]
    gemm_nt<true, true, false><<<dim3(2, 128, 1), 256, 0, stream>>>(
        att_bf, WmT, out, bm, 256, 256, 256, 0, 0, 0, nullptr, nullptr);
}

// Round 4
// 204.824 us; speedup vs baseline: 4.4729x; 1.1252x over previous
//
#include <hip/hip_runtime.h>
#include <hip/hip_bf16.h>
#include <math.h>

#define BB   8
#define NN   2048
#define CC   256
#define MTOT (BB * NN)   // 16384

typedef __bf16 bf16_t;
typedef bf16_t    bf16x8 __attribute__((ext_vector_type(8)));
typedef _Float16  halfx8 __attribute__((ext_vector_type(8)));
typedef float     floatx4 __attribute__((ext_vector_type(4)));

// async global->LDS, 16 bytes per lane. LDS dest must be wave-uniform base + lane*16.
__device__ __forceinline__ void gl_lds16(const bf16_t* g, bf16_t* l) {
    __builtin_amdgcn_global_load_lds(
        (const __attribute__((address_space(1))) unsigned int*)g,
        (__attribute__((address_space(3))) unsigned int*)l, 16, 0, 0);
}

// ---------------------------------------------------------------------------
// NT bf16 GEMM: C[m][n] = sum_k A[m][k] * B[n][k]  (+bias, relu optional)
// 128x128 tile, K fixed = 256, 256 threads (2x2 waves of 64x64), 16x16x32 MFMA.
// OMODE: 0 = fp32 out, 1 = bf16 out, 2 = fp16 out.
// DO_STATS: emit per-column (max, sumexp) partials over this block's 128 rows.
// ---------------------------------------------------------------------------
template<int OMODE, bool BIASRELU, bool DO_STATS>
__global__ __launch_bounds__(256, 3)
void gemm_nt(const bf16_t* __restrict__ A, const bf16_t* __restrict__ B,
             void* __restrict__ C, const float* __restrict__ bias,
             int lda, int ldb, int ldc,
             long strideA, long strideB, long strideC,
             float* __restrict__ pm, float* __restrict__ pl)
{
    const int b = blockIdx.z;
    A += (long)b * strideA;
    B += (long)b * strideB;
    const int m0 = blockIdx.y * 128;
    const int n0 = blockIdx.x * 128;

    __shared__ bf16_t As[128 * 32];
    __shared__ bf16_t Bs[128 * 32];
    __shared__ float  smx[4][4][16];
    __shared__ float  ssm[4][4][16];

    const int tid  = threadIdx.x;
    const int wid  = tid >> 6, lane = tid & 63;
    const int wm   = (wid >> 1) * 64, wn = (wid & 1) * 64;
    const int fr   = lane & 15;
    const int kb   = (lane >> 4) * 8;

    floatx4 acc[4][4] = {};

    for (int k0 = 0; k0 < 256; k0 += 32) {
#pragma unroll
        for (int r = 0; r < 2; ++r) {
            const int lin = tid + r * 256;
            const int rw  = lin >> 2, kc = lin & 3;
            gl_lds16(A + (long)(m0 + rw) * lda + k0 + kc * 8, As + lin * 8);
            gl_lds16(B + (long)(n0 + rw) * ldb + k0 + kc * 8, Bs + lin * 8);
        }
        __syncthreads();
        bf16x8 af[4], bf[4];
#pragma unroll
        for (int f = 0; f < 4; ++f) {
            af[f] = *(const bf16x8*)(As + (wm + f * 16 + fr) * 32 + kb);
            bf[f] = *(const bf16x8*)(Bs + (wn + f * 16 + fr) * 32 + kb);
        }
#pragma unroll
        for (int f = 0; f < 4; ++f)
#pragma unroll
            for (int g = 0; g < 4; ++g)
                acc[f][g] = __builtin_amdgcn_mfma_f32_16x16x32_bf16(af[f], bf[g], acc[f][g], 0, 0, 0);
        __syncthreads();
    }

    // C/D layout: col = lane&15, row = (lane>>4)*4 + reg
    const int rbase = (lane >> 4) * 4;
#pragma unroll
    for (int g = 0; g < 4; ++g) {
        const int n = n0 + wn + g * 16 + fr;
        const float bv = BIASRELU ? bias[n] : 0.0f;
#pragma unroll
        for (int f = 0; f < 4; ++f) {
#pragma unroll
            for (int r = 0; r < 4; ++r) {
                const int m = m0 + wm + f * 16 + rbase + r;
                float v = acc[f][g][r] + bv;
                if (BIASRELU) v = v > 0.0f ? v : 0.0f;
                if (OMODE == 0)
                    ((float*)C)[(long)b * strideC + (long)m * ldc + n] = v;
                else if (OMODE == 1)
                    ((bf16_t*)C)[(long)b * strideC + (long)m * ldc + n] = (bf16_t)v;
                else
                    ((_Float16*)C)[(long)b * strideC + (long)m * ldc + n] = (_Float16)v;
            }
        }
    }

    if (DO_STATS) {
        float lmax[4], lsum[4];
#pragma unroll
        for (int g = 0; g < 4; ++g) {
            float m = -1e30f;
#pragma unroll
            for (int f = 0; f < 4; ++f)
#pragma unroll
                for (int r = 0; r < 4; ++r) m = fmaxf(m, acc[f][g][r]);
            m = fmaxf(m, __shfl_xor(m, 16));
            m = fmaxf(m, __shfl_xor(m, 32));
            float s = 0.0f;
#pragma unroll
            for (int f = 0; f < 4; ++f)
#pragma unroll
                for (int r = 0; r < 4; ++r) s += __expf(acc[f][g][r] - m);
            s += __shfl_xor(s, 16);
            s += __shfl_xor(s, 32);
            lmax[g] = m; lsum[g] = s;
        }
        if (lane < 16) {
#pragma unroll
            for (int g = 0; g < 4; ++g) {
                smx[wid][g][lane] = lmax[g];
                ssm[wid][g][lane] = lsum[g];
            }
        }
        __syncthreads();
        if (tid < 128) {
            const int pair = tid >> 6;
            const int idx  = tid & 63;
            const int g = idx >> 4, f2 = idx & 15;
            const float m0v = smx[pair][g][f2], m1v = smx[pair + 2][g][f2];
            const float M = fmaxf(m0v, m1v);
            const float L = ssm[pair][g][f2] * __expf(m0v - M) +
                            ssm[pair + 2][g][f2] * __expf(m1v - M);
            const int n = n0 + pair * 64 + g * 16 + f2;
            const long o = ((long)b * 16 + blockIdx.y) * NN + n;
            pm[o] = M;
            pl[o] = L;
        }
    }
}

// ---------------------------------------------------------------------------
// Merge 16 per-m-tile partials per column into (mx, invl). 16384 columns.
// ---------------------------------------------------------------------------
__global__ __launch_bounds__(256)
void stats_combine(const float* __restrict__ pm, const float* __restrict__ pl,
                   float* __restrict__ mx, float* __restrict__ invl)
{
    const int i = blockIdx.x * 256 + threadIdx.x;
    const int b = i >> 11, n = i & 2047;
    float M = -1e30f, L = 0.0f;
#pragma unroll
    for (int t = 0; t < 16; ++t) {
        const long o = ((long)b * 16 + t) * NN + n;
        const float m = pm[o], l = pl[o];
        const float nm = fmaxf(M, m);
        L = L * __expf(M - nm) + l * __expf(m - nm);
        M = nm;
    }
    mx[i]   = M;
    invl[i] = 1.0f / L;
}

// ---------------------------------------------------------------------------
// out[m][u] = relu( sum_n exp(St[m][n]-mx[n])*invl[n] * qmT[u][n] + bm[u] )
// St fp16 (m x n per batch), qmT bf16 (u x n per batch). P never materialized;
// final bias+relu fused (out = P~ @ (q@Wm) + bm  ==  (P~ @ q) @ Wm + bm).
// Tile: 64 m x 128 u, K-loop over n in steps of 32. Grid (32, 2, BB) = 512.
// ---------------------------------------------------------------------------
__global__ __launch_bounds__(256, 2)
void att_out(const _Float16* __restrict__ St, const bf16_t* __restrict__ qmT,
             const float* __restrict__ mx, const float* __restrict__ invl,
             const float* __restrict__ bm, float* __restrict__ out)
{
    const int b  = blockIdx.z;
    const int m0 = blockIdx.x * 64;
    const int u0 = blockIdx.y * 128;
    const _Float16* S  = St  + (long)b * NN * NN;
    const bf16_t*   Q  = qmT + (long)b * 256 * NN;
    const float*    MX = mx  + b * NN;
    const float*    IL = invl + b * NN;
    float*          O  = out + (long)b * NN * 256;

    __shared__ bf16_t As[64 * 32];    // 4 KB  P-tile (exp'd, bf16)
    __shared__ bf16_t Bs[128 * 32];   // 8 KB  qmT tile

    const int tid  = threadIdx.x;
    const int wid  = tid >> 6, lane = tid & 63;
    const int wm2  = (wid >> 1) * 32;      // m-half per wave
    const int wu   = (wid & 1) * 64;       // u-half per wave
    const int fr   = lane & 15;
    const int kb   = (lane >> 4) * 8;
    const int arow = tid >> 2;             // 0..63
    const int aseg = tid & 3;              // 8 halves each

    floatx4 acc[2][4] = {};   // [f: m][g: u]

    for (int n0 = 0; n0 < NN; n0 += 32) {
#pragma unroll
        for (int r = 0; r < 2; ++r) {            // qmT: 128 rows x 64 B
            const int lin = tid + r * 256;
            const int rw  = lin >> 2, kc = lin & 3;
            gl_lds16(Q + (long)(u0 + rw) * NN + n0 + kc * 8, Bs + lin * 8);
        }
        // A: load St 64x32 fp16, apply exp(s-mx)*invl, pack bf16
        const halfx8 hv = *(const halfx8*)(S + (long)(m0 + arow) * NN + n0 + aseg * 8);
        const float4 x0 = *(const float4*)(MX + n0 + aseg * 8);
        const float4 x1 = *(const float4*)(MX + n0 + aseg * 8 + 4);
        const float4 i0 = *(const float4*)(IL + n0 + aseg * 8);
        const float4 i1 = *(const float4*)(IL + n0 + aseg * 8 + 4);
        bf16x8 p;
        p[0] = (bf16_t)(__expf((float)hv[0] - x0.x) * i0.x);
        p[1] = (bf16_t)(__expf((float)hv[1] - x0.y) * i0.y);
        p[2] = (bf16_t)(__expf((float)hv[2] - x0.z) * i0.z);
        p[3] = (bf16_t)(__expf((float)hv[3] - x0.w) * i0.w);
        p[4] = (bf16_t)(__expf((float)hv[4] - x1.x) * i1.x);
        p[5] = (bf16_t)(__expf((float)hv[5] - x1.y) * i1.y);
        p[6] = (bf16_t)(__expf((float)hv[6] - x1.z) * i1.z);
        p[7] = (bf16_t)(__expf((float)hv[7] - x1.w) * i1.w);
        *(bf16x8*)(As + arow * 32 + aseg * 8) = p;
        __syncthreads();

        bf16x8 af[2], bfv[4];
#pragma unroll
        for (int f = 0; f < 2; ++f)
            af[f] = *(const bf16x8*)(As + (wm2 + f * 16 + fr) * 32 + kb);
#pragma unroll
        for (int g = 0; g < 4; ++g)
            bfv[g] = *(const bf16x8*)(Bs + (wu + g * 16 + fr) * 32 + kb);
#pragma unroll
        for (int f = 0; f < 2; ++f)
#pragma unroll
            for (int g = 0; g < 4; ++g)
                acc[f][g] = __builtin_amdgcn_mfma_f32_16x16x32_bf16(af[f], bfv[g], acc[f][g], 0, 0, 0);
        __syncthreads();
    }

    const int rbase = (lane >> 4) * 4;
#pragma unroll
    for (int g = 0; g < 4; ++g) {
        const int u = u0 + wu + g * 16 + fr;
        const float bv = bm[u];
#pragma unroll
        for (int f = 0; f < 2; ++f)
#pragma unroll
            for (int r = 0; r < 4; ++r) {
                const int m = m0 + wm2 + f * 16 + rbase + r;
                float v = acc[f][g][r] + bv;
                O[(long)m * 256 + u] = v > 0.0f ? v : 0.0f;
            }
    }
}

// ---------------------------------------------------------------------------
// Helpers
// ---------------------------------------------------------------------------
__global__ __launch_bounds__(256)
void cvt_bf16(const float* __restrict__ x, bf16_t* __restrict__ y)
{
    const long i = ((long)blockIdx.x * 256 + threadIdx.x) * 8;
    const float4 a = *(const float4*)(x + i);
    const float4 b = *(const float4*)(x + i + 4);
    bf16x8 o;
    o[0] = (bf16_t)a.x; o[1] = (bf16_t)a.y; o[2] = (bf16_t)a.z; o[3] = (bf16_t)a.w;
    o[4] = (bf16_t)b.x; o[5] = (bf16_t)b.y; o[6] = (bf16_t)b.z; o[7] = (bf16_t)b.w;
    *(bf16x8*)(y + i) = o;
}

__global__ __launch_bounds__(256)
void transpose_w(const float* __restrict__ W, bf16_t* __restrict__ Wt)
{
    __shared__ float t[32][33];
    const int n0 = blockIdx.x * 32, k0 = blockIdx.y * 32;
    const int tx = threadIdx.x & 31, ty = threadIdx.x >> 5;
    for (int i = ty; i < 32; i += 8) t[i][tx] = W[(k0 + i) * 256 + n0 + tx];
    __syncthreads();
    for (int i = ty; i < 32; i += 8) Wt[(n0 + i) * 256 + k0 + tx] = (bf16_t)t[tx][i];
}

__global__ __launch_bounds__(256)
void transpose_q(const bf16_t* __restrict__ q, bf16_t* __restrict__ qT)
{
    const int b = blockIdx.z;
    const bf16_t* qb = q + (long)b * NN * 256;
    bf16_t* qTb = qT + (long)b * 256 * NN;
    __shared__ bf16_t t[32][33];
    const int n0 = blockIdx.x * 32, h0 = blockIdx.y * 32;
    const int tx = threadIdx.x & 31, ty = threadIdx.x >> 5;
    for (int i = ty; i < 32; i += 8) t[i][tx] = qb[(long)(n0 + i) * 256 + h0 + tx];
    __syncthreads();
    for (int i = ty; i < 32; i += 8) qTb[(long)(h0 + i) * NN + n0 + tx] = t[tx][i];
}

__global__ __launch_bounds__(256)
void concat_bias(const float* __restrict__ a, const float* __restrict__ b,
                 float* __restrict__ o)
{
    const int i = blockIdx.x * 256 + threadIdx.x;   // 512 total
    o[i] = (i < 256) ? a[i] : b[i - 256];
}

extern "C" void kernel_launch(void* const* d_in, const int* in_sizes, int n_in,
                              void* d_out, int out_size, void* d_ws, size_t ws_size,
                              hipStream_t stream)
{
    (void)in_sizes; (void)n_in; (void)out_size; (void)ws_size;
    const float* x  = (const float*)d_in[0];
    const float* Wq = (const float*)d_in[1];
    const float* bq = (const float*)d_in[2];
    const float* Wk = (const float*)d_in[3];
    const float* bk = (const float*)d_in[4];
    const float* Wm = (const float*)d_in[5];
    const float* bm = (const float*)d_in[6];
    float* out = (float*)d_out;

    // Workspace: St fp16 67.1 MB | x_bf 8.4 | qk 16.8 | qm 8.4 | qmT 8.4 |
    // WqkT 0.25 | WmT 0.125 | bqk | pm/pl 2x1 MB | mx/il 2x64 KB  (~111 MB)
    char* w = (char*)d_ws;
    _Float16* St   = (_Float16*)w;                  w += (size_t)BB * NN * NN * 2;
    bf16_t* x_bf   = (bf16_t*)w;                    w += (size_t)MTOT * 256 * 2;
    bf16_t* qk     = (bf16_t*)w;                    w += (size_t)MTOT * 512 * 2;
    bf16_t* qm     = (bf16_t*)w;                    w += (size_t)MTOT * 256 * 2;
    bf16_t* qmT    = (bf16_t*)w;                    w += (size_t)MTOT * 256 * 2;
    bf16_t* WqkT   = (bf16_t*)w;                    w += 512 * 256 * 2;
    bf16_t* WmT    = (bf16_t*)w;                    w += 256 * 256 * 2;
    float*  bqk    = (float*)w;                     w += 512 * 4;
    float*  pm     = (float*)w;                     w += (size_t)BB * 16 * NN * 4;
    float*  pl     = (float*)w;                     w += (size_t)BB * 16 * NN * 4;
    float*  mxb    = (float*)w;                     w += MTOT * 4;
    float*  ilb    = (float*)w;

    cvt_bf16<<<dim3(MTOT * 256 / (256 * 8)), 256, 0, stream>>>(x, x_bf);
    transpose_w<<<dim3(8, 8), 256, 0, stream>>>(Wq, WqkT);              // rows 0..255
    transpose_w<<<dim3(8, 8), 256, 0, stream>>>(Wk, WqkT + 256 * 256);  // rows 256..511
    transpose_w<<<dim3(8, 8), 256, 0, stream>>>(Wm, WmT);
    concat_bias<<<dim3(2), 256, 0, stream>>>(bq, bk, bqk);

    // [q | k] = relu(x @ [Wq|Wk] + [bq|bk])  (bf16, ldc=512)
    gemm_nt<1, true, false><<<dim3(4, 128, 1), 256, 0, stream>>>(
        x_bf, WqkT, qk, bqk, 256, 256, 512, 0, 0, 0, nullptr, nullptr);

    // qm = q @ Wm  (NO bias/relu here; bm folded into att_out epilogue)
    gemm_nt<1, false, false><<<dim3(2, 128, 1), 256, 0, stream>>>(
        qk, WmT, qm, nullptr, 512, 256, 256, 0, 0, 0, nullptr, nullptr);

    transpose_q<<<dim3(64, 8, 8), 256, 0, stream>>>(qm, qmT);

    // St[m][n] = q[m]·k[n]  (fp16 out) + fused per-column softmax stats
    gemm_nt<2, false, true><<<dim3(16, 16, BB), 256, 0, stream>>>(
        qk, qk + 256, St, nullptr, 512, 512, NN,
        (long)NN * 512, (long)NN * 512, (long)NN * NN, pm, pl);

    stats_combine<<<dim3(MTOT / 256), 256, 0, stream>>>(pm, pl, mxb, ilb);

    // out = relu(P~ @ qm + bm)
    att_out<<<dim3(32, 2, BB), 256, 0, stream>>>(St, qmT, mxb, ilb, bm, out);
}